// Round 8
// baseline (555.288 us; speedup 1.0000x reference)
//
#include <hip/hip_runtime.h>

#define TPB 256
#define NWAVE (TPB / 64)
#define GRID_MAIN 2048

typedef int vi2 __attribute__((ext_vector_type(2)));
typedef int vi4 __attribute__((ext_vector_type(4)));

// Cumulative wave-chunk ends (chunks of 64 terms): bond, angle, torsion, inversion, LJ.
struct SegInfo {
    int cb, ca, ct, ci, cl;
    int NB, NA, NT, NI, NC;
    int N;
};

__device__ __forceinline__ float clamp1(float x) {
    return fminf(fmaxf(x, -0.999999f), 0.999999f);
}

__device__ __forceinline__ float ntf(const float* p) { return __builtin_nontemporal_load(p); }
__device__ __forceinline__ int   nti(const int* p)   { return __builtin_nontemporal_load(p); }

// cw layout: float4[atom][8] — atom's 8 batch replicas contiguous (128 B aligned).
// The 8 lanes of a term-group each load one dwordx4 -> one 128B region per gather.
template <bool USE_WS>
__device__ __forceinline__ float4 loadC(const float4* __restrict__ cw,
                                        const float* __restrict__ coords,
                                        int N, int atom, int b) {
    if (USE_WS) {
        return cw[((size_t)atom << 3) + b];
    } else {
        const float* sp = coords + ((size_t)b * N + atom) * 3;
        return make_float4(sp[0], sp[1], sp[2], 0.f);
    }
}

// coords (B,N,3) -> cw float4[atom][8]; also zeroes d_out and the work counter.
__global__ void __launch_bounds__(TPB) transpose_coords(const float* __restrict__ coords,
                                                        float4* __restrict__ cw,
                                                        float* __restrict__ out,
                                                        int* __restrict__ ctr, int N) {
    const int a = blockIdx.x * TPB + threadIdx.x;
    if (blockIdx.x == 0) {
        if (threadIdx.x < 8) out[threadIdx.x] = 0.f;
        if (threadIdx.x == 8) *ctr = 0;
    }
    if (a >= N) return;
#pragma unroll
    for (int b = 0; b < 8; b++) {
        const float* sp = coords + ((size_t)b * N + a) * 3;
        cw[((size_t)a << 3) + b] = make_float4(ntf(sp), ntf(sp + 1), ntf(sp + 2), 0.f);
    }
}

template <bool USE_WS>
__global__ void __launch_bounds__(TPB) uff_kernel(
    const float* __restrict__ coords, const float4* __restrict__ cw,
    const int* __restrict__ bidx, const float* __restrict__ br0, const float* __restrict__ bk,
    const int* __restrict__ aidx, const float* __restrict__ ak,
    const float* __restrict__ ac0, const float* __restrict__ ac1, const float* __restrict__ ac2,
    const int* __restrict__ tidx, const float* __restrict__ tk,
    const int* __restrict__ tord, const float* __restrict__ tcos,
    const int* __restrict__ iidx, const float* __restrict__ ik,
    const float* __restrict__ ic0, const float* __restrict__ ic1, const float* __restrict__ ic2,
    const int* __restrict__ nidx, const float* __restrict__ vmin,
    const float* __restrict__ vdep, const float* __restrict__ vthr,
    int* __restrict__ ctr, float* __restrict__ out, SegInfo s)
{
    // Per-wave staging slice: 64 terms' indices+params (8 KB/block). No barriers:
    // only the owning wave reads its slice (same-wave ds ordering via lgkmcnt).
    __shared__ int4   sI[NWAVE][64];
    __shared__ float4 sP[NWAVE][64];

    const int tid = threadIdx.x;
    const int lane = tid & 63;
    const int w = tid >> 6;
    const int b = lane & 7;       // this lane's batch
    const int gw = lane >> 3;     // group within wave, 0..7
    const int N = s.N;
    float acc = 0.f;

    int4*   mI = sI[w];
    float4* mP = sP[w];

    // Dynamic work-stealing: each wave grabs 64-term chunks until exhausted.
    while (true) {
        int c = 0;
        if (lane == 0) c = atomicAdd(ctr, 1);
        c = __shfl(c, 0, 64);      // wave-uniform chunk id
        if (c >= s.cl) break;

        int kind, base;
        if (c < s.cb)      { kind = 0; base = c * 64; }
        else if (c < s.ca) { kind = 1; base = (c - s.cb) * 64; }
        else if (c < s.ct) { kind = 2; base = (c - s.ca) * 64; }
        else if (c < s.ci) { kind = 3; base = (c - s.ct) * 64; }
        else               { kind = 4; base = (c - s.ci) * 64; }

        // ---------------- stage this wave's 64 terms ----------------
        if (kind == 0) {
            const int u = min(base + lane, s.NB - 1);
            const vi2 ij = __builtin_nontemporal_load((const vi2*)bidx + u);
            mI[lane] = make_int4(ij.x, ij.y, 0, 0);
            mP[lane] = make_float4(ntf(br0 + u), ntf(bk + u), 0.f, 0.f);
        } else if (kind == 1) {
            const int u = min(base + lane, s.NA - 1);
            mI[lane] = make_int4(aidx[3 * u], aidx[3 * u + 1], aidx[3 * u + 2], 0);
            mP[lane] = make_float4(ntf(ak + u), ntf(ac0 + u), ntf(ac1 + u), ntf(ac2 + u));
        } else if (kind == 2) {
            const int u = min(base + lane, s.NT - 1);
            const vi4 q = __builtin_nontemporal_load((const vi4*)tidx + u);
            mI[lane] = make_int4(q.x, q.y, q.z, q.w);
            mP[lane] = make_float4(ntf(tk + u), ntf(tcos + u),
                                   __int_as_float(nti(tord + u)), 0.f);
        } else if (kind == 3) {
            const int u = min(base + lane, s.NI - 1);
            const vi4 q = __builtin_nontemporal_load((const vi4*)iidx + u);  // i, central, k, l
            mI[lane] = make_int4(q.x, q.y, q.z, q.w);
            mP[lane] = make_float4(ntf(ik + u), ntf(ic0 + u), ntf(ic1 + u), ntf(ic2 + u));
        } else {
            const int u = min(base + lane, s.NC - 1);
            const vi2 ij = __builtin_nontemporal_load((const vi2*)nidx + u);
            const float R = ntf(vmin + u);
            mI[lane] = make_int4(ij.x, ij.y, 0, 0);
            mP[lane] = make_float4(R * R, ntf(vdep + u), ntf(vthr + u), 0.f);
        }
        // (compiler inserts s_waitcnt lgkmcnt before the reads below — same-wave LDS)

        // ---------------- process: 8 lanes per term, one batch per lane ----------------
        if (kind == 4) {
            // vdW LJ: 2 terms per group per iteration (4 gathers in flight)
#pragma unroll
            for (int j = 0; j < 4; j++) {
                const int s0 = j * 8 + gw, s1 = s0 + 32;
                const int4 q0 = mI[s0]; const float4 p0 = mP[s0];
                const int4 q1 = mI[s1]; const float4 p1 = mP[s1];
                float4 a0 = loadC<USE_WS>(cw, coords, N, q0.x, b);
                float4 b0 = loadC<USE_WS>(cw, coords, N, q0.y, b);
                float4 a1 = loadC<USE_WS>(cw, coords, N, q1.x, b);
                float4 b1 = loadC<USE_WS>(cw, coords, N, q1.y, b);
                {
                    float dx = a0.x - b0.x, dy = a0.y - b0.y, dz = a0.z - b0.z;
                    float d2 = dx * dx + dy * dy + dz * dz;
                    float x2 = p0.x / fmaxf(d2, 1e-12f);
                    float x6 = x2 * x2 * x2;
                    float e = p0.y * (x6 * x6 - 2.f * x6);
                    if (base + s0 < s.NC && d2 <= p0.z) acc += e;
                }
                {
                    float dx = a1.x - b1.x, dy = a1.y - b1.y, dz = a1.z - b1.z;
                    float d2 = dx * dx + dy * dy + dz * dz;
                    float x2 = p1.x / fmaxf(d2, 1e-12f);
                    float x6 = x2 * x2 * x2;
                    float e = p1.y * (x6 * x6 - 2.f * x6);
                    if (base + s1 < s.NC && d2 <= p1.z) acc += e;
                }
            }
        } else if (kind == 0) {
            // bond stretch
#pragma unroll 2
            for (int j = 0; j < 8; j++) {
                const int slot = j * 8 + gw;
                const int4 q = mI[slot]; const float4 p = mP[slot];
                float4 ci = loadC<USE_WS>(cw, coords, N, q.x, b);
                float4 cj = loadC<USE_WS>(cw, coords, N, q.y, b);
                float dx = ci.x - cj.x, dy = ci.y - cj.y, dz = ci.z - cj.z;
                float dd = sqrtf(dx * dx + dy * dy + dz * dz) - p.x;
                if (base + slot < s.NB) acc += 0.5f * p.y * dd * dd;
            }
        } else if (kind == 1) {
            // angle bend
#pragma unroll 2
            for (int j = 0; j < 8; j++) {
                const int slot = j * 8 + gw;
                const int4 q = mI[slot]; const float4 p = mP[slot];
                float4 P = loadC<USE_WS>(cw, coords, N, q.x, b);
                float4 Q = loadC<USE_WS>(cw, coords, N, q.y, b);
                float4 R = loadC<USE_WS>(cw, coords, N, q.z, b);
                float ax = P.x - Q.x, ay = P.y - Q.y, az = P.z - Q.z;
                float bx = R.x - Q.x, by = R.y - Q.y, bz = R.z - Q.z;
                float dot = ax * bx + ay * by + az * bz;
                float nn = (ax * ax + ay * ay + az * az) * (bx * bx + by * by + bz * bz);
                float ct = clamp1(dot * rsqrtf(fmaxf(nn, 1e-24f)));
                float cs = ct * ct;
                float sb = fmaxf(1.f - cs, 1e-12f);
                if (base + slot < s.NA) acc += p.x * (p.y + p.z * ct + p.w * (cs - sb));
            }
        } else if (kind == 2) {
            // torsion
#pragma unroll 2
            for (int j = 0; j < 8; j++) {
                const int slot = j * 8 + gw;
                const int4 q = mI[slot]; const float4 p = mP[slot];
                const int ord = __float_as_int(p.z);
                float4 P1 = loadC<USE_WS>(cw, coords, N, q.x, b);
                float4 P2 = loadC<USE_WS>(cw, coords, N, q.y, b);
                float4 P3 = loadC<USE_WS>(cw, coords, N, q.z, b);
                float4 P4 = loadC<USE_WS>(cw, coords, N, q.w, b);
                float b1x = P2.x - P1.x, b1y = P2.y - P1.y, b1z = P2.z - P1.z;
                float b2x = P3.x - P2.x, b2y = P3.y - P2.y, b2z = P3.z - P2.z;
                float b3x = P4.x - P3.x, b3y = P4.y - P3.y, b3z = P4.z - P3.z;
                float n1x = b1y * b2z - b1z * b2y;
                float n1y = b1z * b2x - b1x * b2z;
                float n1z = b1x * b2y - b1y * b2x;
                float n2x = b2y * b3z - b2z * b3y;
                float n2y = b2z * b3x - b2x * b3z;
                float n2z = b2x * b3y - b2y * b3x;
                float dot = n1x * n2x + n1y * n2y + n1z * n2z;
                float nn = (n1x * n1x + n1y * n1y + n1z * n1z) *
                           (n2x * n2x + n2y * n2y + n2z * n2z);
                float x = clamp1(dot * rsqrtf(fmaxf(nn, 1e-24f)));
                // cos(n*acos(x)) = T_n(x), n in [1,6]
                float Tp = 1.f, Tc = x, res = x;
#pragma unroll
                for (int kk = 2; kk <= 6; kk++) {
                    float Tn = 2.f * x * Tc - Tp;
                    Tp = Tc; Tc = Tn;
                    if (ord == kk) res = Tn;
                }
                if (base + slot < s.NT) acc += 0.5f * p.x * (1.f - p.y * res);
            }
        } else {
            // inversion (Wilson)
#pragma unroll 2
            for (int j = 0; j < 8; j++) {
                const int slot = j * 8 + gw;
                const int4 q = mI[slot]; const float4 p = mP[slot];
                float4 CA = loadC<USE_WS>(cw, coords, N, q.y, b);
                float4 PI = loadC<USE_WS>(cw, coords, N, q.x, b);
                float4 PK = loadC<USE_WS>(cw, coords, N, q.z, b);
                float4 PL = loadC<USE_WS>(cw, coords, N, q.w, b);
                float jix = PI.x - CA.x, jiy = PI.y - CA.y, jiz = PI.z - CA.z;
                float jkx = PK.x - CA.x, jky = PK.y - CA.y, jkz = PK.z - CA.z;
                float lx  = PL.x - CA.x, ly  = PL.y - CA.y, lz  = PL.z - CA.z;
                float nx = jiy * jkz - jiz * jky;
                float ny = jiz * jkx - jix * jkz;
                float nz = jix * jky - jiy * jkx;
                float dot = nx * lx + ny * ly + nz * lz;
                float nn = (nx * nx + ny * ny + nz * nz) * (lx * lx + ly * ly + lz * lz);
                float cosY = clamp1(dot * rsqrtf(fmaxf(nn, 1e-24f)));
                float sinY = sqrtf(fmaxf(1.f - cosY * cosY, 0.f));
                if (base + slot < s.NI)
                    acc += p.x * (p.y + p.z * sinY + p.w * (2.f * sinY * sinY - 1.f));
            }
        }
    }

    // ---------------- reduction: lanes with same (lane&7) hold same batch ----------------
    float v = acc;
    v += __shfl_down(v, 8, 64);
    v += __shfl_down(v, 16, 64);
    v += __shfl_down(v, 32, 64);
    // lanes 0..7 of each wave now hold batch 0..7 sums

    __shared__ float red[NWAVE][8];
    if (lane < 8) red[w][lane] = v;
    __syncthreads();
    if (tid < 8) {
        float ssum = 0.f;
#pragma unroll
        for (int i = 0; i < NWAVE; i++) ssum += red[i][tid];
        atomicAdd(&out[tid], ssum);
    }
}

static inline int cdiv(int a, int b) { return (a + b - 1) / b; }

extern "C" void kernel_launch(void* const* d_in, const int* in_sizes, int n_in,
                              void* d_out, int out_size, void* d_ws, size_t ws_size,
                              hipStream_t stream) {
    const int B = out_size;  // expected 8 (kernel hard-codes 8 batches)
    const int NB = in_sizes[2], NA = in_sizes[5], NT = in_sizes[10],
              NI = in_sizes[14], NC = in_sizes[19];
    const int N = in_sizes[0] / (3 * B);

    const float* coords = (const float*)d_in[0];
    const int*   bidx = (const int*)d_in[1];
    const float* br0  = (const float*)d_in[2];
    const float* bk   = (const float*)d_in[3];
    const int*   aidx = (const int*)d_in[4];
    const float* ak   = (const float*)d_in[5];
    const float* ac0  = (const float*)d_in[6];
    const float* ac1  = (const float*)d_in[7];
    const float* ac2  = (const float*)d_in[8];
    const int*   tidx = (const int*)d_in[9];
    const float* tk   = (const float*)d_in[10];
    const int*   tord = (const int*)d_in[11];
    const float* tcos = (const float*)d_in[12];
    const int*   iidx = (const int*)d_in[13];
    const float* ik   = (const float*)d_in[14];
    const float* ic0  = (const float*)d_in[15];
    const float* ic1  = (const float*)d_in[16];
    const float* ic2  = (const float*)d_in[17];
    const int*   nidx = (const int*)d_in[18];
    const float* vmin = (const float*)d_in[19];
    const float* vdep = (const float*)d_in[20];
    const float* vthr = (const float*)d_in[21];

    const size_t cw_bytes = (size_t)N * 8 * sizeof(float4);
    const bool use_ws = ws_size >= cw_bytes + sizeof(int);
    float4* cw = (float4*)d_ws;
    int* ctr;

    if (use_ws) {
        ctr = (int*)((char*)d_ws + cw_bytes);
        transpose_coords<<<cdiv(N, TPB), TPB, 0, stream>>>(coords, cw, (float*)d_out, ctr, N);
    } else {
        ctr = (int*)d_ws;
        hipMemsetAsync(d_out, 0, (size_t)out_size * sizeof(float), stream);
        hipMemsetAsync(d_ws, 0, sizeof(int), stream);
    }

    SegInfo s;
    s.NB = NB; s.NA = NA; s.NT = NT; s.NI = NI; s.NC = NC; s.N = N;
    s.cb = cdiv(NB, 64);
    s.ca = s.cb + cdiv(NA, 64);
    s.ct = s.ca + cdiv(NT, 64);
    s.ci = s.ct + cdiv(NI, 64);
    s.cl = s.ci + cdiv(NC, 64);

    if (use_ws) {
        uff_kernel<true><<<GRID_MAIN, TPB, 0, stream>>>(
            coords, cw, bidx, br0, bk, aidx, ak, ac0, ac1, ac2,
            tidx, tk, tord, tcos, iidx, ik, ic0, ic1, ic2,
            nidx, vmin, vdep, vthr, ctr, (float*)d_out, s);
    } else {
        uff_kernel<false><<<GRID_MAIN, TPB, 0, stream>>>(
            coords, cw, bidx, br0, bk, aidx, ak, ac0, ac1, ac2,
            tidx, tk, tord, tcos, iidx, ik, ic0, ic1, ic2,
            nidx, vmin, vdep, vthr, ctr, (float*)d_out, s);
    }
}

// Round 9
// 168.956 us; speedup vs baseline: 3.2866x; 3.2866x over previous
//
#include <hip/hip_runtime.h>

#define TPB 256
#define NWAVE (TPB / 64)
#define GRID_MAIN 2048

typedef int vi2 __attribute__((ext_vector_type(2)));
typedef int vi4 __attribute__((ext_vector_type(4)));

// Unified chunk space (64-term chunks), cumulative ends: bond|angle|torsion|inversion|LJ.
struct SegInfo {
    int cb, ca, ct, ci, cl;
    int NB, NA, NT, NI, NC;
    int N;
};

__device__ __forceinline__ float clamp1(float x) {
    return fminf(fmaxf(x, -0.999999f), 0.999999f);
}

__device__ __forceinline__ float ntf(const float* p) { return __builtin_nontemporal_load(p); }
__device__ __forceinline__ int   nti(const int* p)   { return __builtin_nontemporal_load(p); }

// cw layout: float4[atom][8] — atom's 8 batch replicas contiguous (128 B aligned).
// The 8 lanes of a term-group each load one dwordx4 -> one 128B region per gather.
template <bool USE_WS>
__device__ __forceinline__ float4 loadC(const float4* __restrict__ cw,
                                        const float* __restrict__ coords,
                                        int N, int atom, int b) {
    if (USE_WS) {
        return cw[((size_t)atom << 3) + b];
    } else {
        const float* sp = coords + ((size_t)b * N + atom) * 3;
        return make_float4(sp[0], sp[1], sp[2], 0.f);
    }
}

// coords (B,N,3) -> cw float4[atom][8]; also zeroes d_out.
__global__ void __launch_bounds__(TPB) transpose_coords(const float* __restrict__ coords,
                                                        float4* __restrict__ cw,
                                                        float* __restrict__ out, int N) {
    const int a = blockIdx.x * TPB + threadIdx.x;
    if (blockIdx.x == 0 && threadIdx.x < 8) out[threadIdx.x] = 0.f;
    if (a >= N) return;
#pragma unroll
    for (int b = 0; b < 8; b++) {
        const float* sp = coords + ((size_t)b * N + a) * 3;
        cw[((size_t)a << 3) + b] = make_float4(ntf(sp), ntf(sp + 1), ntf(sp + 2), 0.f);
    }
}

// Load chunk c's term-(lane) indices+params into registers (one term per lane).
__device__ __forceinline__ void stage(
    int c, const SegInfo& s, int lane,
    const int* __restrict__ bidx, const float* __restrict__ br0, const float* __restrict__ bk,
    const int* __restrict__ aidx, const float* __restrict__ ak,
    const float* __restrict__ ac0, const float* __restrict__ ac1, const float* __restrict__ ac2,
    const int* __restrict__ tidx, const float* __restrict__ tk,
    const int* __restrict__ tord, const float* __restrict__ tcos,
    const int* __restrict__ iidx, const float* __restrict__ ik,
    const float* __restrict__ ic0, const float* __restrict__ ic1, const float* __restrict__ ic2,
    const int* __restrict__ nidx, const float* __restrict__ vmin,
    const float* __restrict__ vdep, const float* __restrict__ vthr,
    int4& ri, float4& rp)
{
    if (c < s.cb) {
        const int u = min(c * 64 + lane, s.NB - 1);
        const vi2 ij = __builtin_nontemporal_load((const vi2*)bidx + u);
        ri = make_int4(ij.x, ij.y, 0, 0);
        rp = make_float4(ntf(br0 + u), ntf(bk + u), 0.f, 0.f);
    } else if (c < s.ca) {
        const int u = min((c - s.cb) * 64 + lane, s.NA - 1);
        ri = make_int4(aidx[3 * u], aidx[3 * u + 1], aidx[3 * u + 2], 0);
        rp = make_float4(ntf(ak + u), ntf(ac0 + u), ntf(ac1 + u), ntf(ac2 + u));
    } else if (c < s.ct) {
        const int u = min((c - s.ca) * 64 + lane, s.NT - 1);
        const vi4 q = __builtin_nontemporal_load((const vi4*)tidx + u);
        ri = make_int4(q.x, q.y, q.z, q.w);
        rp = make_float4(ntf(tk + u), ntf(tcos + u), __int_as_float(nti(tord + u)), 0.f);
    } else if (c < s.ci) {
        const int u = min((c - s.ct) * 64 + lane, s.NI - 1);
        const vi4 q = __builtin_nontemporal_load((const vi4*)iidx + u);  // i, central, k, l
        ri = make_int4(q.x, q.y, q.z, q.w);
        rp = make_float4(ntf(ik + u), ntf(ic0 + u), ntf(ic1 + u), ntf(ic2 + u));
    } else {
        const int u = min((c - s.ci) * 64 + lane, s.NC - 1);
        const vi2 ij = __builtin_nontemporal_load((const vi2*)nidx + u);
        const float R = ntf(vmin + u);
        ri = make_int4(ij.x, ij.y, 0, 0);
        rp = make_float4(R * R, ntf(vdep + u), ntf(vthr + u), 0.f);
    }
}

template <bool USE_WS>
__global__ void __launch_bounds__(TPB) uff_kernel(
    const float* __restrict__ coords, const float4* __restrict__ cw,
    const int* __restrict__ bidx, const float* __restrict__ br0, const float* __restrict__ bk,
    const int* __restrict__ aidx, const float* __restrict__ ak,
    const float* __restrict__ ac0, const float* __restrict__ ac1, const float* __restrict__ ac2,
    const int* __restrict__ tidx, const float* __restrict__ tk,
    const int* __restrict__ tord, const float* __restrict__ tcos,
    const int* __restrict__ iidx, const float* __restrict__ ik,
    const float* __restrict__ ic0, const float* __restrict__ ic1, const float* __restrict__ ic2,
    const int* __restrict__ nidx, const float* __restrict__ vmin,
    const float* __restrict__ vdep, const float* __restrict__ vthr,
    float* __restrict__ out, SegInfo s)
{
    // Per-wave staging slice (8 KB/block). Barrier-free: only the owning wave
    // touches its slice (same-wave ds ordering via lgkmcnt).
    __shared__ int4   sI[NWAVE][64];
    __shared__ float4 sP[NWAVE][64];

    const int tid = threadIdx.x;
    const int lane = tid & 63;
    const int w = tid >> 6;
    const int b = lane & 7;       // this lane's batch
    const int gw = lane >> 3;     // group within wave, 0..7
    const int N = s.N;
    float acc = 0.f;

    int4*   mI = sI[w];
    float4* mP = sP[w];

    const int stride = gridDim.x * NWAVE;
    int c = blockIdx.x * NWAVE + w;

    // Software pipeline: prefetch chunk c's params into registers.
    int4 ri; float4 rp;
    if (c < s.cl)
        stage(c, s, lane, bidx, br0, bk, aidx, ak, ac0, ac1, ac2,
              tidx, tk, tord, tcos, iidx, ik, ic0, ic1, ic2,
              nidx, vmin, vdep, vthr, ri, rp);

    while (c < s.cl) {
        // Commit prefetched params to LDS (waits vmcnt for the prefetch loads —
        // covered by the previous iteration's compute).
        mI[lane] = ri;
        mP[lane] = rp;

        int kind, base;
        if (c < s.cb)      { kind = 0; base = c * 64; }
        else if (c < s.ca) { kind = 1; base = (c - s.cb) * 64; }
        else if (c < s.ct) { kind = 2; base = (c - s.ca) * 64; }
        else if (c < s.ci) { kind = 3; base = (c - s.ct) * 64; }
        else               { kind = 4; base = (c - s.ci) * 64; }

        // Issue next chunk's staging loads (independent of this chunk's compute).
        const int cn = c + stride;
        if (cn < s.cl)
            stage(cn, s, lane, bidx, br0, bk, aidx, ak, ac0, ac1, ac2,
                  tidx, tk, tord, tcos, iidx, ik, ic0, ic1, ic2,
                  nidx, vmin, vdep, vthr, ri, rp);

        // ---------------- process: 8 lanes per term, one batch per lane ----------------
        if (kind == 4) {
            // vdW LJ: 2 terms per group per iteration (4 gathers in flight)
#pragma unroll
            for (int j = 0; j < 4; j++) {
                const int s0 = j * 8 + gw, s1 = s0 + 32;
                const int4 q0 = mI[s0]; const float4 p0 = mP[s0];
                const int4 q1 = mI[s1]; const float4 p1 = mP[s1];
                float4 a0 = loadC<USE_WS>(cw, coords, N, q0.x, b);
                float4 b0 = loadC<USE_WS>(cw, coords, N, q0.y, b);
                float4 a1 = loadC<USE_WS>(cw, coords, N, q1.x, b);
                float4 b1 = loadC<USE_WS>(cw, coords, N, q1.y, b);
                {
                    float dx = a0.x - b0.x, dy = a0.y - b0.y, dz = a0.z - b0.z;
                    float d2 = dx * dx + dy * dy + dz * dz;
                    float x2 = p0.x / fmaxf(d2, 1e-12f);
                    float x6 = x2 * x2 * x2;
                    float e = p0.y * (x6 * x6 - 2.f * x6);
                    if (base + s0 < s.NC && d2 <= p0.z) acc += e;
                }
                {
                    float dx = a1.x - b1.x, dy = a1.y - b1.y, dz = a1.z - b1.z;
                    float d2 = dx * dx + dy * dy + dz * dz;
                    float x2 = p1.x / fmaxf(d2, 1e-12f);
                    float x6 = x2 * x2 * x2;
                    float e = p1.y * (x6 * x6 - 2.f * x6);
                    if (base + s1 < s.NC && d2 <= p1.z) acc += e;
                }
            }
        } else if (kind == 0) {
            // bond stretch
#pragma unroll 2
            for (int j = 0; j < 8; j++) {
                const int slot = j * 8 + gw;
                const int4 q = mI[slot]; const float4 p = mP[slot];
                float4 ci = loadC<USE_WS>(cw, coords, N, q.x, b);
                float4 cj = loadC<USE_WS>(cw, coords, N, q.y, b);
                float dx = ci.x - cj.x, dy = ci.y - cj.y, dz = ci.z - cj.z;
                float dd = sqrtf(dx * dx + dy * dy + dz * dz) - p.x;
                if (base + slot < s.NB) acc += 0.5f * p.y * dd * dd;
            }
        } else if (kind == 1) {
            // angle bend
#pragma unroll 2
            for (int j = 0; j < 8; j++) {
                const int slot = j * 8 + gw;
                const int4 q = mI[slot]; const float4 p = mP[slot];
                float4 P = loadC<USE_WS>(cw, coords, N, q.x, b);
                float4 Q = loadC<USE_WS>(cw, coords, N, q.y, b);
                float4 R = loadC<USE_WS>(cw, coords, N, q.z, b);
                float ax = P.x - Q.x, ay = P.y - Q.y, az = P.z - Q.z;
                float bx = R.x - Q.x, by = R.y - Q.y, bz = R.z - Q.z;
                float dot = ax * bx + ay * by + az * bz;
                float nn = (ax * ax + ay * ay + az * az) * (bx * bx + by * by + bz * bz);
                float ct = clamp1(dot * rsqrtf(fmaxf(nn, 1e-24f)));
                float cs = ct * ct;
                float sb = fmaxf(1.f - cs, 1e-12f);
                if (base + slot < s.NA) acc += p.x * (p.y + p.z * ct + p.w * (cs - sb));
            }
        } else if (kind == 2) {
            // torsion
#pragma unroll 2
            for (int j = 0; j < 8; j++) {
                const int slot = j * 8 + gw;
                const int4 q = mI[slot]; const float4 p = mP[slot];
                const int ord = __float_as_int(p.z);
                float4 P1 = loadC<USE_WS>(cw, coords, N, q.x, b);
                float4 P2 = loadC<USE_WS>(cw, coords, N, q.y, b);
                float4 P3 = loadC<USE_WS>(cw, coords, N, q.z, b);
                float4 P4 = loadC<USE_WS>(cw, coords, N, q.w, b);
                float b1x = P2.x - P1.x, b1y = P2.y - P1.y, b1z = P2.z - P1.z;
                float b2x = P3.x - P2.x, b2y = P3.y - P2.y, b2z = P3.z - P2.z;
                float b3x = P4.x - P3.x, b3y = P4.y - P3.y, b3z = P4.z - P3.z;
                float n1x = b1y * b2z - b1z * b2y;
                float n1y = b1z * b2x - b1x * b2z;
                float n1z = b1x * b2y - b1y * b2x;
                float n2x = b2y * b3z - b2z * b3y;
                float n2y = b2z * b3x - b2x * b3z;
                float n2z = b2x * b3y - b2y * b3x;
                float dot = n1x * n2x + n1y * n2y + n1z * n2z;
                float nn = (n1x * n1x + n1y * n1y + n1z * n1z) *
                           (n2x * n2x + n2y * n2y + n2z * n2z);
                float x = clamp1(dot * rsqrtf(fmaxf(nn, 1e-24f)));
                // cos(n*acos(x)) = T_n(x), n in [1,6]
                float Tp = 1.f, Tc = x, res = x;
#pragma unroll
                for (int kk = 2; kk <= 6; kk++) {
                    float Tn = 2.f * x * Tc - Tp;
                    Tp = Tc; Tc = Tn;
                    if (ord == kk) res = Tn;
                }
                if (base + slot < s.NT) acc += 0.5f * p.x * (1.f - p.y * res);
            }
        } else {
            // inversion (Wilson)
#pragma unroll 2
            for (int j = 0; j < 8; j++) {
                const int slot = j * 8 + gw;
                const int4 q = mI[slot]; const float4 p = mP[slot];
                float4 CA = loadC<USE_WS>(cw, coords, N, q.y, b);
                float4 PI = loadC<USE_WS>(cw, coords, N, q.x, b);
                float4 PK = loadC<USE_WS>(cw, coords, N, q.z, b);
                float4 PL = loadC<USE_WS>(cw, coords, N, q.w, b);
                float jix = PI.x - CA.x, jiy = PI.y - CA.y, jiz = PI.z - CA.z;
                float jkx = PK.x - CA.x, jky = PK.y - CA.y, jkz = PK.z - CA.z;
                float lx  = PL.x - CA.x, ly  = PL.y - CA.y, lz  = PL.z - CA.z;
                float nx = jiy * jkz - jiz * jky;
                float ny = jiz * jkx - jix * jkz;
                float nz = jix * jky - jiy * jkx;
                float dot = nx * lx + ny * ly + nz * lz;
                float nn = (nx * nx + ny * ny + nz * nz) * (lx * lx + ly * ly + lz * lz);
                float cosY = clamp1(dot * rsqrtf(fmaxf(nn, 1e-24f)));
                float sinY = sqrtf(fmaxf(1.f - cosY * cosY, 0.f));
                if (base + slot < s.NI)
                    acc += p.x * (p.y + p.z * sinY + p.w * (2.f * sinY * sinY - 1.f));
            }
        }

        c = cn;
    }

    // ---------------- reduction: lanes with same (lane&7) hold same batch ----------------
    float v = acc;
    v += __shfl_down(v, 8, 64);
    v += __shfl_down(v, 16, 64);
    v += __shfl_down(v, 32, 64);
    // lanes 0..7 of each wave now hold batch 0..7 sums

    __shared__ float red[NWAVE][8];
    if (lane < 8) red[w][lane] = v;
    __syncthreads();
    if (tid < 8) {
        float ssum = 0.f;
#pragma unroll
        for (int i = 0; i < NWAVE; i++) ssum += red[i][tid];
        atomicAdd(&out[tid], ssum);
    }
}

static inline int cdiv(int a, int b) { return (a + b - 1) / b; }

extern "C" void kernel_launch(void* const* d_in, const int* in_sizes, int n_in,
                              void* d_out, int out_size, void* d_ws, size_t ws_size,
                              hipStream_t stream) {
    const int B = out_size;  // expected 8 (kernel hard-codes 8 batches)
    const int NB = in_sizes[2], NA = in_sizes[5], NT = in_sizes[10],
              NI = in_sizes[14], NC = in_sizes[19];
    const int N = in_sizes[0] / (3 * B);

    const float* coords = (const float*)d_in[0];
    const int*   bidx = (const int*)d_in[1];
    const float* br0  = (const float*)d_in[2];
    const float* bk   = (const float*)d_in[3];
    const int*   aidx = (const int*)d_in[4];
    const float* ak   = (const float*)d_in[5];
    const float* ac0  = (const float*)d_in[6];
    const float* ac1  = (const float*)d_in[7];
    const float* ac2  = (const float*)d_in[8];
    const int*   tidx = (const int*)d_in[9];
    const float* tk   = (const float*)d_in[10];
    const int*   tord = (const int*)d_in[11];
    const float* tcos = (const float*)d_in[12];
    const int*   iidx = (const int*)d_in[13];
    const float* ik   = (const float*)d_in[14];
    const float* ic0  = (const float*)d_in[15];
    const float* ic1  = (const float*)d_in[16];
    const float* ic2  = (const float*)d_in[17];
    const int*   nidx = (const int*)d_in[18];
    const float* vmin = (const float*)d_in[19];
    const float* vdep = (const float*)d_in[20];
    const float* vthr = (const float*)d_in[21];

    const size_t cw_bytes = (size_t)N * 8 * sizeof(float4);
    const bool use_ws = ws_size >= cw_bytes;
    float4* cw = (float4*)d_ws;

    if (use_ws) {
        transpose_coords<<<cdiv(N, TPB), TPB, 0, stream>>>(coords, cw, (float*)d_out, N);
    } else {
        hipMemsetAsync(d_out, 0, (size_t)out_size * sizeof(float), stream);
    }

    SegInfo s;
    s.NB = NB; s.NA = NA; s.NT = NT; s.NI = NI; s.NC = NC; s.N = N;
    s.cb = cdiv(NB, 64);
    s.ca = s.cb + cdiv(NA, 64);
    s.ct = s.ca + cdiv(NT, 64);
    s.ci = s.ct + cdiv(NI, 64);
    s.cl = s.ci + cdiv(NC, 64);

    if (use_ws) {
        uff_kernel<true><<<GRID_MAIN, TPB, 0, stream>>>(
            coords, cw, bidx, br0, bk, aidx, ak, ac0, ac1, ac2,
            tidx, tk, tord, tcos, iidx, ik, ic0, ic1, ic2,
            nidx, vmin, vdep, vthr, (float*)d_out, s);
    } else {
        uff_kernel<false><<<GRID_MAIN, TPB, 0, stream>>>(
            coords, cw, bidx, br0, bk, aidx, ak, ac0, ac1, ac2,
            tidx, tk, tord, tcos, iidx, ik, ic0, ic1, ic2,
            nidx, vmin, vdep, vthr, (float*)d_out, s);
    }
}